// Round 6
// baseline (28.002 us; speedup 1.0000x reference)
//
#include <hip/hip_runtime.h>

#define NATOMS  1024
#define NB      32
#define LUTN    2048                   // bins per class over b in [0,1)
#define NCLASS  3
#define LUTSZ   (LUTN * NCLASS)        // 6144 floats = 24 KB
#define WS_PART 8192                   // float offset of partials in d_ws

#define BLK     512                    // 8 waves per block
#define WPB     8
#define BPBATCH 32                     // blocks per batch
#define WAVES   (BPBATCH * WPB)        // 256 waves per batch
#define PPW     ((NATOMS / 2) / WAVES) // 2 row-pairs per wave

// Kernel 0: build the LUT once per call (6144 accurate evaluations).
// f_s(b) = d0_s * b * exp(p1_s * (1 - b^p2_s)), sampled at bin centers.
__global__ void reax_lut(const float* __restrict__ d0t,
                         const float* __restrict__ p1t,
                         const float* __restrict__ p2t,
                         float* __restrict__ lut)
{
    const int t = blockIdx.x * blockDim.x + threadIdx.x;
    if (t >= LUTSZ) return;
    const int s = t >> 11;             // class 0,1,2
    const int i = t & (LUTN - 1);
    const int tbl = (s == 0) ? 4 : (s == 1) ? 5 : 8;  // [1][1],[1][2],[2][2]
    const float d0 = d0t[tbl], p1 = p1t[tbl], p2 = p2t[tbl];
    const float bc = ((float)i + 0.5f) * (1.0f / (float)LUTN);
    lut[t] = d0 * bc * expf(p1 * (1.0f - powf(bc, p2)));
}

// Kernel 1: per-(batch, wave) partial sums over the strict lower triangle.
// Inner body: fma(|x|,8192,o) -> cvt_u32 -> and ~3 -> ds_read_b32 -> add.
// o = t_i*8192 bytes (per-element, staged in LDS); t_j*8192 folded into the
// ds_read immediate offset via a uniform per-row branch.
__global__ __launch_bounds__(BLK) void reax_partial(
    const int*   __restrict__ Z,
    const float* __restrict__ B,
    const float* __restrict__ lutg,
    float*       __restrict__ ws)
{
    __shared__ float lut_sh[LUTSZ + 4];   // +pad for the rare round-up edge
    __shared__ float o_shf[NATOMS];       // t_i * 8192.0f (byte offset)

    const int b    = blockIdx.y;
    const int wave = blockIdx.x * WPB + (threadIdx.x >> 6);
    const int lane = threadIdx.x & 63;

    for (int i = threadIdx.x; i < LUTSZ; i += BLK) lut_sh[i] = lutg[i];
    if (threadIdx.x < 4) lut_sh[LUTSZ + threadIdx.x] = lutg[LUTSZ - 1];
    const int* Zrow = Z + b * NATOMS;
    for (int i = threadIdx.x; i < NATOMS; i += BLK)
        o_shf[i] = (Zrow[i] == 8) ? 8192.0f : 0.0f;
    __syncthreads();

    const float* Bb = B + (size_t)b * NATOMS * NATOMS;
    float sum0 = 0.0f, sum1 = 0.0f;

    // LOFF is a compile-time byte offset -> folds into ds_read offset imm.
    #define ELEM(xc, oc, acc, LOFF)                                          \
    {                                                                        \
        const float    fb = fmaf(fabsf(xc), 8192.0f, oc);                    \
        const unsigned bi = ((unsigned)fb) & ~3u;                            \
        acc += *(const float*)((const char*)lut_sh + (LOFF) + bi);           \
    }

    #define ROWBODY(LOFF)                                                    \
    {                                                                        \
        const float4* Brow4 = (const float4*)Brow;                           \
        const float4* Orow4 = (const float4*)o_shf;                          \
        const int nv = j >> 2;                                               \
        for (int v = lane; v < nv; v += 64) {                                \
            const float4 x = Brow4[v];                                       \
            const float4 o = Orow4[v];                                       \
            ELEM(x.x, o.x, sum0, LOFF) ELEM(x.y, o.y, sum1, LOFF)            \
            ELEM(x.z, o.z, sum0, LOFF) ELEM(x.w, o.w, sum1, LOFF)            \
        }                                                                    \
        const int ti = (nv << 2) + lane;                                     \
        if (ti < j) ELEM(Brow[ti], o_shf[ti], sum0, LOFF)                    \
    }

    for (int pp = 0; pp < PPW; ++pp) {
        const int p = wave + pp * WAVES;   // 0..511
        #pragma unroll
        for (int r = 0; r < 2; ++r) {
            const int j = r ? (NATOMS - 1 - p) : p;
            if (j == 0) continue;
            const float* Brow = Bb + (size_t)j * NATOMS;
            if (o_shf[j] == 0.0f) {        // t_j = 0
                ROWBODY(0)
            } else {                       // t_j = 1 -> +2048 entries
                ROWBODY(8192)
            }
        }
    }
    #undef ROWBODY
    #undef ELEM

    float sum = sum0 + sum1;
    #pragma unroll
    for (int off = 32; off; off >>= 1) sum += __shfl_down(sum, off, 64);
    if (lane == 0) ws[WS_PART + b * WAVES + wave] = sum;
}

// Kernel 2: one 64-lane wave per batch reduces the WAVES partials.
__global__ __launch_bounds__(64) void reax_reduce(
    const float* __restrict__ ws, float* __restrict__ out)
{
    const int b = blockIdx.x;
    const int t = threadIdx.x;
    const float* p = ws + WS_PART + b * WAVES;
    float s = p[t] + p[t + 64] + p[t + 128] + p[t + 192];
    #pragma unroll
    for (int off = 32; off; off >>= 1) s += __shfl_down(s, off, 64);
    if (t == 0) out[b] = -s;   // e_ij carries the leading minus sign
}

extern "C" void kernel_launch(void* const* d_in, const int* in_sizes, int n_in,
                              void* d_out, int out_size, void* d_ws, size_t ws_size,
                              hipStream_t stream) {
    const int*   Z   = (const int*)  d_in[0];
    const float* B   = (const float*)d_in[1];
    const float* d0t = (const float*)d_in[2];
    const float* p1t = (const float*)d_in[3];
    const float* p2t = (const float*)d_in[4];
    float* out = (float*)d_out;
    float* ws  = (float*)d_ws;   // [0,6144): LUT; [8192,16384): partials

    reax_lut<<<(LUTSZ + 255) / 256, 256, 0, stream>>>(d0t, p1t, p2t, ws);
    dim3 grid(BPBATCH, NB);
    reax_partial<<<grid, BLK, 0, stream>>>(Z, B, ws, ws);
    reax_reduce<<<NB, 64, 0, stream>>>(ws, out);
}

// Round 8
// 26.670 us; speedup vs baseline: 1.0500x; 1.0500x over previous
//
#include <hip/hip_runtime.h>

typedef float v4f __attribute__((ext_vector_type(4)));

#define NATOMS  1024
#define NB      32
#define WPB     4                  // waves per block
#define BLK     (WPB * 64)         // 256 threads
#define BPBATCH 32                 // blocks per batch (longer-lived waves)
#define WAVES   (BPBATCH * WPB)    // 128 waves per batch
#define PPW     ((NATOMS / 2) / WAVES)  // 4 row-pairs per wave

// e = d0*b*exp(p1*(1-b^p2)) with class s = t_i+t_j in {0,1,2}:
//   e = de * exp2(lg + c1*exp2(p2*lg)),  lg = log2|b|,
//   de = d0*e^p1, c1 = -p1*log2(e).   (b=0 -> lg=-inf -> e=0, matches ref.)
// Params linear in t_i in {0,1}. Memory-bound: B rows streamed once with
// nontemporal float4 loads; fewer, longer-lived waves cut latency tails.
__global__ __launch_bounds__(BLK) void reax_partial(
    const int*   __restrict__ Z,
    const float* __restrict__ B,
    const float* __restrict__ d0t,
    const float* __restrict__ p1t,
    const float* __restrict__ p2t,
    float*       __restrict__ ws)
{
    const int b    = blockIdx.y;
    const int wave = blockIdx.x * WPB + (threadIdx.x >> 6);
    const int lane = threadIdx.x & 63;

    const float LOG2E = 1.4426950408889634f;
    const float d0_0 = d0t[4], d0_1 = d0t[5], d0_2 = d0t[8];
    const float p1_0 = p1t[4], p1_1 = p1t[5], p1_2 = p1t[8];
    const float p2_0 = p2t[4], p2_1 = p2t[5], p2_2 = p2t[8];
    const float de_0 = d0_0 * __builtin_amdgcn_exp2f(p1_0 * LOG2E);
    const float de_1 = d0_1 * __builtin_amdgcn_exp2f(p1_1 * LOG2E);
    const float de_2 = d0_2 * __builtin_amdgcn_exp2f(p1_2 * LOG2E);
    const float c1_0 = -p1_0 * LOG2E, c1_1 = -p1_1 * LOG2E, c1_2 = -p1_2 * LOG2E;

    __shared__ float t_shf[NATOMS];     // atom type as float (0.0 / 1.0)
    const int* Zrow = Z + b * NATOMS;
    for (int i = threadIdx.x; i < NATOMS; i += BLK)
        t_shf[i] = (Zrow[i] == 8) ? 1.0f : 0.0f;
    __syncthreads();

    const float* Bb = B + (size_t)b * NATOMS * NATOMS;
    float sum0 = 0.0f, sum1 = 0.0f;

    for (int pp = 0; pp < PPW; ++pp) {
        const int p = wave + pp * WAVES;   // 0..511
        #pragma unroll
        for (int r = 0; r < 2; ++r) {
            const int j = r ? (NATOMS - 1 - p) : p;
            if (j == 0) continue;
            const int tj = (t_shf[j] != 0.0f);
            const float dea = tj ? de_1 : de_0, dde = tj ? (de_2 - de_1) : (de_1 - de_0);
            const float c1a = tj ? c1_1 : c1_0, dc1 = tj ? (c1_2 - c1_1) : (c1_1 - c1_0);
            const float p2a = tj ? p2_1 : p2_0, dp2 = tj ? (p2_2 - p2_1) : (p2_1 - p2_0);

            const float* Brow  = Bb + (size_t)j * NATOMS;
            const v4f*   Brow4 = (const v4f*)Brow;
            const v4f*   Trow4 = (const v4f*)t_shf;
            const int nv = j >> 2;

            #define ELEM(xc, tc, acc)                                       \
            {                                                               \
                const float bb  = fabsf(xc);                                \
                const float p2  = fmaf(tc, dp2, p2a);                       \
                const float c1  = fmaf(tc, dc1, c1a);                       \
                const float de  = fmaf(tc, dde, dea);                       \
                const float lg  = __builtin_amdgcn_logf(bb);                \
                const float pw  = __builtin_amdgcn_exp2f(p2 * lg);          \
                const float ex  = __builtin_amdgcn_exp2f(fmaf(c1, pw, lg)); \
                acc = fmaf(de, ex, acc);                                    \
            }

            #pragma unroll 2
            for (int v = lane; v < nv; v += 64) {
                const v4f x  = __builtin_nontemporal_load(&Brow4[v]);
                const v4f t4 = Trow4[v];
                ELEM(x.x, t4.x, sum0) ELEM(x.y, t4.y, sum1)
                ELEM(x.z, t4.z, sum0) ELEM(x.w, t4.w, sum1)
            }
            // tail: up to 3 elements
            const int i = (nv << 2) + lane;
            if (i < j) {
                ELEM(Brow[i], t_shf[i], sum0)
            }
            #undef ELEM
        }
    }

    float sum = sum0 + sum1;
    #pragma unroll
    for (int off = 32; off; off >>= 1) sum += __shfl_down(sum, off, 64);
    if (lane == 0) ws[b * WAVES + wave] = sum;
}

// Stage 2: one 64-lane wave per batch reduces the WAVES partials.
__global__ __launch_bounds__(64) void reax_reduce(
    const float* __restrict__ ws, float* __restrict__ out)
{
    const int b = blockIdx.x;
    const int t = threadIdx.x;
    const float* p = ws + b * WAVES;
    float s = p[t] + p[t + 64];
    #pragma unroll
    for (int off = 32; off; off >>= 1) s += __shfl_down(s, off, 64);
    if (t == 0) out[b] = -s;   // e_ij carries the leading minus sign
}

extern "C" void kernel_launch(void* const* d_in, const int* in_sizes, int n_in,
                              void* d_out, int out_size, void* d_ws, size_t ws_size,
                              hipStream_t stream) {
    const int*   Z   = (const int*)  d_in[0];
    const float* B   = (const float*)d_in[1];
    const float* d0t = (const float*)d_in[2];
    const float* p1t = (const float*)d_in[3];
    const float* p2t = (const float*)d_in[4];
    float* out = (float*)d_out;
    float* ws  = (float*)d_ws;   // NB*WAVES floats, fully rewritten every call

    dim3 grid(BPBATCH, NB);
    reax_partial<<<grid, BLK, 0, stream>>>(Z, B, d0t, p1t, p2t, ws);
    reax_reduce<<<NB, 64, 0, stream>>>(ws, out);
}